// Round 7
// baseline (881.819 us; speedup 1.0000x reference)
//
#include <hip/hip_runtime.h>

// Fused RNN: encoders + 576-step LSTM + projection + softmax.
// 256 blocks x 512 threads, 4 batches/block, 1 block/CU.
//
// Round-7: ONE barrier per step; gates never leave registers.
//  - W~ columns permuted gate-major (n' = 4g+gate): tile ti = all 4 gates of
//    g in [4ti,4ti+4). MFMA D: quad of lanes 0..15 holds (gate x batch) 4x4.
//  - 16-op DPP quad transpose (0xB1 / 0x4E butterfly) -> lane qp holds gates
//    {i,f,g,o} of (g, batch=qp) in its 4 regs; sigmoid/tanh + c_state update +
//    f16 h-write all in-register. Z table + activation phase + 1 barrier gone.
//  - Wave 7: projection split into 4 independent dot2 accumulators (chain 50->13);
//    encoder staging software-pipelined 2 steps ahead (raw rows prefetched into
//    regs; staging branch runs BEFORE projection so its loads overlap the chain).

#define NTHR 512

typedef _Float16 half8 __attribute__((ext_vector_type(8)));
typedef _Float16 h2    __attribute__((ext_vector_type(2)));
typedef _Float16 h4v   __attribute__((ext_vector_type(4)));
typedef _Float16 h8v   __attribute__((ext_vector_type(8)));
typedef float    f32x4 __attribute__((ext_vector_type(4)));

struct __align__(16) SM {
  _Float16 Y[2][16][136];  // [phase][m(batch,4 used)][k]: h(0..99), s(100..108), 1(109), 0 pad
  float w_in[81], w_task[81];
  float b_in[9], b_task[9];
};

__device__ __forceinline__ float dot2(h2 a, h2 b, float c) {
#if defined(__has_builtin)
#if __has_builtin(__builtin_amdgcn_fdot2)
  return __builtin_amdgcn_fdot2(a, b, c, false);
#else
  return fmaf((float)a.x, (float)b.x, fmaf((float)a.y, (float)b.y, c));
#endif
#else
  return fmaf((float)a.x, (float)b.x, fmaf((float)a.y, (float)b.y, c));
#endif
}

__device__ __forceinline__ float dppB1(float v) {  // quad_perm(1,0,3,2): xor lane-bit0
  return __int_as_float(__builtin_amdgcn_update_dpp(0, __float_as_int(v), 0xB1, 0xF, 0xF, true));
}
__device__ __forceinline__ float dpp4E(float v) {  // quad_perm(2,3,0,1): xor lane-bit1
  return __int_as_float(__builtin_amdgcn_update_dpp(0, __float_as_int(v), 0x4E, 0xF, 0xF, true));
}

__device__ __forceinline__ float fast_sigmoid(float x) {
  return __builtin_amdgcn_rcpf(1.f + __expf(-x));
}
__device__ __forceinline__ float fast_tanh(float x) {
  return fmaf(2.f, __builtin_amdgcn_rcpf(1.f + __expf(-2.f * x)), -1.f);
}

// W~ row k of ORIGINAL column col: k<100 -> W_h, 100..108 -> W_x, 109 -> b_lstm, else 0.
__device__ __forceinline__ float wld(int k, int col,
                                     const float* __restrict__ Wh,
                                     const float* __restrict__ Wx,
                                     const float* __restrict__ bl) {
  if (k < 100)  return Wh[k * 400 + col];
  if (k < 109)  return Wx[(k - 100) * 400 + col];
  if (k == 109) return bl[col];
  return 0.f;
}

__global__ __launch_bounds__(NTHR, 2)
void lstm_fused(const float* __restrict__ g_input,
                const float* __restrict__ g_task,
                const float* __restrict__ g_Win,
                const float* __restrict__ g_bin,
                const float* __restrict__ g_Wtask,
                const float* __restrict__ g_btask,
                const float* __restrict__ g_Wx,
                const float* __restrict__ g_Wh,
                const float* __restrict__ g_bl,
                const float* __restrict__ g_Wout,
                const float* __restrict__ g_bout,
                float* __restrict__ g_out)
{
  __shared__ SM L;
  const int tid  = threadIdx.x;
  const int bg0  = blockIdx.x * 4;
  const int wv   = tid >> 6;        // wave id 0..7
  const int lane = tid & 63;
  const int q    = lane >> 4;       // MFMA k-chunk quad
  const int nl   = lane & 15;       // n-within-tile (B) / m=batch row (A)

  // ---- cooperative LDS fill: Y = 0 except k==109 -> 1.0 (bias slot) ----
  for (int i = tid; i < 2 * 16 * 136; i += NTHR)
    ((_Float16*)L.Y)[i] = ((i % 136) == 109) ? (_Float16)1.f : (_Float16)0.f;
  for (int i = tid; i < 81; i += NTHR) { L.w_in[i] = g_Win[i]; L.w_task[i] = g_Wtask[i]; }
  if (tid < 9) { L.b_in[tid] = g_bin[tid]; L.b_task[tid] = g_btask[tid]; }

  // ---- MFMA tile ownership (waves 0..6): 25 N'-tiles, clamped dups benign ----
  const int tbase = (wv < 4) ? wv * 4 : 16 + 3 * (wv - 4);

  // ---- B-fragments: permuted W~ (n' = 4g+gate), weight-stationary ----
  half8 Bf[4][4];   // [ti][kc]: lane holds B[k=32kc+8q+j][n'=16*tile+nl]
  if (wv < 7) {
#pragma unroll
    for (int ti = 0; ti < 4; ++ti) {
      const int tile = min(tbase + ti, 24);
      const int np   = tile * 16 + nl;          // permuted col
      const int col  = (np & 3) * 100 + (np >> 2);  // original col (g<=99 always)
#pragma unroll
      for (int kc = 0; kc < 4; ++kc) {
#pragma unroll
        for (int j = 0; j < 8; ++j)
          Bf[ti][kc][j] = (_Float16)wld(kc * 32 + q * 8 + j, col, g_Wh, g_Wx, g_bl);
      }
    }
  }

  // ---- wave-7 roles ----
  const int el = tid - 448;                         // wave-7 lane
  const int eb = (el >= 0 && el < 36) ? el / 9 : 0; // projection batch
  const int od = (el >= 0 && el < 36) ? el % 9 : 0; // projection out-dim
  const int sl = tid - 484;                         // staging lane 0..27
  const int sbA = (sl >= 0) ? sl / 9 : 0, sfA = (sl >= 0) ? sl % 9 : 0;       // item A
  const int jB  = sl + 28;                                                     // item B (sl<8)
  const int sbB = (jB < 36) ? jB / 9 : 0, sfB = (jB < 36) ? jB % 9 : 0;
  h2 wout[50];
  float breg = 0.f;
  if (wv == 7 && el < 36) {
#pragma unroll
    for (int j = 0; j < 50; ++j) {
      h2 h; h.x = (_Float16)g_Wout[(2 * j) * 9 + od];
      h.y = (_Float16)g_Wout[(2 * j + 1) * 9 + od];
      wout[j] = h;
    }
    breg = g_bout[od];
  }

  float cst[4] = {0.f, 0.f, 0.f, 0.f};  // dot lanes<16: c_state per tile
  float nxtA[9], nxtB[9];               // staging prefetch regs (raw input rows)

  __syncthreads();

  // ---- prologue (staging lanes): encode s[0] -> Y[0]; prefetch raw row 1 ----
  if (tid >= 484) {
#pragma unroll 1
    for (int pass = 0; pass < 2; ++pass) {
      const int j = sl + pass * 28;
      if (j < 36) {
        const int b = j / 9, f = j % 9;
        const float* src = g_input + (long)(bg0 + b) * 512 * 9;
        float a = L.b_in[f];
#pragma unroll
        for (int ff = 0; ff < 9; ++ff) a = fmaf(src[ff], L.w_in[ff * 9 + f], a);
        L.Y[0][b][100 + f] = (_Float16)fmaxf(a, 0.f);
      }
    }
    {
      const float* srcA = g_input + ((long)(bg0 + sbA) * 512 + 1) * 9;
#pragma unroll
      for (int ff = 0; ff < 9; ++ff) nxtA[ff] = srcA[ff];
      if (sl < 8) {
        const float* srcB = g_input + ((long)(bg0 + sbB) * 512 + 1) * 9;
#pragma unroll
        for (int ff = 0; ff < 9; ++ff) nxtB[ff] = srcB[ff];
      }
    }
  }
  __syncthreads();

  // ---- main recurrence: ONE barrier per step ----
  for (int t = 0; t < 576; ++t) {
    const int p = t & 1;
    if (wv < 7) {
      // A-fragments: batch rows of fused state y
      half8 A[4];
#pragma unroll
      for (int kc = 0; kc < 4; ++kc)
        A[kc] = *(const half8*)&L.Y[p][nl][kc * 32 + q * 8];
      f32x4 acc[4];
#pragma unroll
      for (int ti = 0; ti < 4; ++ti) {
        acc[ti] = (f32x4)0.f;
#pragma unroll
        for (int kc = 0; kc < 4; ++kc)
          acc[ti] = __builtin_amdgcn_mfma_f32_16x16x32_f16(A[kc], Bf[ti][kc], acc[ti], 0, 0, 0);
      }
      if (lane < 16) {
        const int qp   = lane & 3;    // after transpose: my batch
        const int grow = lane >> 2;   // g offset within tile
        const bool s0 = qp & 1, s1 = qp & 2;
#pragma unroll
        for (int ti = 0; ti < 4; ++ti) {
          const int tile = min(tbase + ti, 24);
          const int gidx = 4 * tile + grow;   // <= 99 always
          // 4x4 quad transpose: (lane=gate, reg=batch) -> (lane=batch, reg=gate)
          float a0 = acc[ti].x, a1 = acc[ti].y, a2 = acc[ti].z, a3 = acc[ti].w;
          const float x0 = dppB1(a1), x1 = dppB1(a0), x2 = dppB1(a3), x3 = dppB1(a2);
          const float b0 = s0 ? x0 : a0;
          const float b1 = s0 ? a1 : x1;
          const float b2 = s0 ? x2 : a2;
          const float b3 = s0 ? a3 : x3;
          const float y0 = dpp4E(b2), y1 = dpp4E(b3), y2 = dpp4E(b0), y3 = dpp4E(b1);
          const float zi = s1 ? y0 : b0;
          const float zf = s1 ? y1 : b1;
          const float zg = s1 ? b2 : y2;
          const float zo = s1 ? b3 : y3;
          const float gi = fast_sigmoid(zi);
          const float gf = fast_sigmoid(zf);
          const float gg = fast_tanh(zg);
          const float go = fast_sigmoid(zo);
          cst[ti] = fmaf(gf, cst[ti], gi * gg);
          L.Y[p ^ 1][qp][gidx] = (_Float16)(go * fast_tanh(cst[ti]));
        }
      }
    } else if (el >= 36) {
      // ---- staging: encode s[t+1] from prefetched regs; prefetch row t+2 ----
      const int tt = t + 1;
      if (tt < 576) {
        const float* wm = (tt < 512) ? L.w_in : L.w_task;
        const float* bm = (tt < 512) ? L.b_in : L.b_task;
        {
          float a = bm[sfA];
#pragma unroll
          for (int ff = 0; ff < 9; ++ff) a = fmaf(nxtA[ff], wm[ff * 9 + sfA], a);
          L.Y[tt & 1][sbA][100 + sfA] = (_Float16)fmaxf(a, 0.f);
        }
        if (sl < 8) {
          float a = bm[sfB];
#pragma unroll
          for (int ff = 0; ff < 9; ++ff) a = fmaf(nxtB[ff], wm[ff * 9 + sfB], a);
          L.Y[tt & 1][sbB][100 + sfB] = (_Float16)fmaxf(a, 0.f);
        }
      }
      const int t2 = t + 2;
      if (t2 < 576) {
        const float* srcA = (t2 < 512) ? g_input + ((long)(bg0 + sbA) * 512 + t2) * 9
                                       : g_task  + ((long)(bg0 + sbA) * 64 + (t2 - 512)) * 9;
#pragma unroll
        for (int ff = 0; ff < 9; ++ff) nxtA[ff] = srcA[ff];
        if (sl < 8) {
          const float* srcB = (t2 < 512) ? g_input + ((long)(bg0 + sbB) * 512 + t2) * 9
                                         : g_task  + ((long)(bg0 + sbB) * 64 + (t2 - 512)) * 9;
#pragma unroll
          for (int ff = 0; ff < 9; ++ff) nxtB[ff] = srcB[ff];
        }
      }
    } else if (t > 0) {
      // ---- projection + softmax for step t-1 (h[t-1] in Y[p]) ----
      const _Float16* yr = &L.Y[p][eb][0];
      float l0 = breg, l1 = 0.f, l2 = 0.f, l3 = 0.f;
#pragma unroll
      for (int j = 0; j < 12; ++j) {
        const h8v v = *(const h8v*)(yr + 8 * j);
        l0 = dot2(wout[4 * j + 0], __builtin_shufflevector(v, v, 0, 1), l0);
        l1 = dot2(wout[4 * j + 1], __builtin_shufflevector(v, v, 2, 3), l1);
        l2 = dot2(wout[4 * j + 2], __builtin_shufflevector(v, v, 4, 5), l2);
        l3 = dot2(wout[4 * j + 3], __builtin_shufflevector(v, v, 6, 7), l3);
      }
      const h4v tail = *(const h4v*)(yr + 96);
      l0 = dot2(wout[48], __builtin_shufflevector(tail, tail, 0, 1), l0);
      l1 = dot2(wout[49], __builtin_shufflevector(tail, tail, 2, 3), l1);
      const float lg = (l0 + l1) + (l2 + l3);
      const int lane0 = eb * 9;
      float m = lg;
#pragma unroll
      for (int j = 0; j < 9; ++j) m = fmaxf(m, __shfl(lg, lane0 + j, 64));
      const float e = __expf(lg - m);
      float ssum = 0.f;
#pragma unroll
      for (int j = 0; j < 9; ++j) ssum += __shfl(e, lane0 + j, 64);
      g_out[((long)(bg0 + eb) * 576 + (t - 1)) * 9 + od] = e * __builtin_amdgcn_rcpf(ssum);
    }
    __syncthreads();
  }

  // ---- tail: projection for t=575 (h[575] in Y[0]) ----
  if (wv == 7 && el < 36) {
    const _Float16* yr = &L.Y[0][eb][0];
    float l0 = breg, l1 = 0.f, l2 = 0.f, l3 = 0.f;
#pragma unroll
    for (int j = 0; j < 12; ++j) {
      const h8v v = *(const h8v*)(yr + 8 * j);
      l0 = dot2(wout[4 * j + 0], __builtin_shufflevector(v, v, 0, 1), l0);
      l1 = dot2(wout[4 * j + 1], __builtin_shufflevector(v, v, 2, 3), l1);
      l2 = dot2(wout[4 * j + 2], __builtin_shufflevector(v, v, 4, 5), l2);
      l3 = dot2(wout[4 * j + 3], __builtin_shufflevector(v, v, 6, 7), l3);
    }
    const h4v tail = *(const h4v*)(yr + 96);
    l0 = dot2(wout[48], __builtin_shufflevector(tail, tail, 0, 1), l0);
    l1 = dot2(wout[49], __builtin_shufflevector(tail, tail, 2, 3), l1);
    const float lg = (l0 + l1) + (l2 + l3);
    const int lane0 = eb * 9;
    float m = lg;
#pragma unroll
    for (int j = 0; j < 9; ++j) m = fmaxf(m, __shfl(lg, lane0 + j, 64));
    const float e = __expf(lg - m);
    float ssum = 0.f;
#pragma unroll
    for (int j = 0; j < 9; ++j) ssum += __shfl(e, lane0 + j, 64);
    g_out[((long)(bg0 + eb) * 576 + 575) * 9 + od] = e * __builtin_amdgcn_rcpf(ssum);
  }
}

extern "C" void kernel_launch(void* const* d_in, const int* in_sizes, int n_in,
                              void* d_out, int out_size, void* d_ws, size_t ws_size,
                              hipStream_t stream) {
  const float* input  = (const float*)d_in[0];
  const float* task   = (const float*)d_in[1];
  const float* W_in   = (const float*)d_in[2];
  const float* b_in   = (const float*)d_in[3];
  const float* W_task = (const float*)d_in[4];
  const float* b_task = (const float*)d_in[5];
  const float* W_x    = (const float*)d_in[6];
  const float* W_h    = (const float*)d_in[7];
  const float* b_lstm = (const float*)d_in[8];
  const float* W_out  = (const float*)d_in[9];
  const float* b_out  = (const float*)d_in[10];
  float* out = (float*)d_out;

  lstm_fused<<<256, NTHR, 0, stream>>>(input, task, W_in, b_in, W_task, b_task,
                                       W_x, W_h, b_lstm, W_out, b_out, out);
}